// Round 2
// baseline (151.783 us; speedup 1.0000x reference)
//
#include <hip/hip_runtime.h>
#include <math.h>

#define BB 8192
#define DD 768
#define EE 16
#define PP 4
#define ROWS_PER_BLK 16   // K1: rows per block (4 per wave)

// ---------------- K1: gating (router + top2 + softmax + permute + averages) ----
__global__ __launch_bounds__(256) void gating_kernel(
    const float* __restrict__ x,     // [B, D]
    const float* __restrict__ W,     // [E, D]
    const float* __restrict__ bias,  // [E]
    const float* __restrict__ Pw,    // [P, E, E]
    float* __restrict__ sp_ws,       // [B, E] scratch
    float* __restrict__ avgs)        // [32]: soft[16], hard[16]
{
    __shared__ float Pm[EE * EE];
    __shared__ float aS[EE], aH[EE];

    const int t = threadIdx.x;

    // P_mean = mean over the 4 permutation matrices -> LDS (one entry/thread)
    {
        float s = 0.f;
        #pragma unroll
        for (int p = 0; p < PP; ++p) s += Pw[p * EE * EE + t];
        Pm[t] = s * 0.25f;
    }
    if (t < EE) { aS[t] = 0.f; aH[t] = 0.f; }
    __syncthreads();

    const int wave = t >> 6;        // 0..3
    const int lane = t & 63;
    const int r_in = lane >> 4;     // 0..3 (row within wave)
    const int e    = lane & 15;     // expert
    const int row  = blockIdx.x * ROWS_PER_BLK + wave * 4 + r_in;

    // logit = dot(x[row], W[e]) + bias[e]  (one full dot per lane, float4)
    const float4* x4 = (const float4*)(x + (size_t)row * DD);
    const float4* w4 = (const float4*)(W + (size_t)e * DD);
    float4 acc = {0.f, 0.f, 0.f, 0.f};
    #pragma unroll 4
    for (int k = 0; k < DD / 4; ++k) {
        float4 a = x4[k], b = w4[k];
        acc.x = fmaf(a.x, b.x, acc.x);
        acc.y = fmaf(a.y, b.y, acc.y);
        acc.z = fmaf(a.z, b.z, acc.z);
        acc.w = fmaf(a.w, b.w, acc.w);
    }
    const float logit = acc.x + acc.y + acc.z + acc.w + bias[e];

    // top-1 (val,idx) across the 16 lanes of this row group
    float v0 = logit; int i0 = e;
    #pragma unroll
    for (int m = 1; m < 16; m <<= 1) {
        float ov = __shfl_xor(v0, m, 16);
        int   oi = __shfl_xor(i0, m, 16);
        if (ov > v0 || (ov == v0 && oi < i0)) { v0 = ov; i0 = oi; }
    }
    // top-2: mask out i0, reduce again
    float v1 = (e == i0) ? -INFINITY : logit; int i1 = e;
    #pragma unroll
    for (int m = 1; m < 16; m <<= 1) {
        float ov = __shfl_xor(v1, m, 16);
        int   oi = __shfl_xor(i1, m, 16);
        if (ov > v1 || (ov == v1 && oi < i1)) { v1 = ov; i1 = oi; }
    }

    // reference quirk: scattered==0.0 -> -inf before softmax
    const float z0 = (v0 == 0.f) ? -INFINITY : v0;
    const float z1 = (v1 == 0.f) ? -INFINITY : v1;
    const float mx = fmaxf(z0, z1);
    const float e0 = expf(z0 - mx), e1 = expf(z1 - mx);
    const float inv = 1.f / (e0 + e1);
    const float sm0 = e0 * inv, sm1 = e1 * inv;

    // s_perm[row, e] = sm0*Pm[i0,e] + sm1*Pm[i1,e]
    const float s = sm0 * Pm[i0 * EE + e] + sm1 * Pm[i1 * EE + e];
    sp_ws[(size_t)row * EE + e] = s;   // wave writes 256 contiguous bytes

    // block-local average accumulation (reduce 4 rows within wave via shfl)
    float ssum = s;
    float hsum = (s >= 1e-5f) ? 1.f : 0.f;
    ssum += __shfl_xor(ssum, 16, 64);
    ssum += __shfl_xor(ssum, 32, 64);
    hsum += __shfl_xor(hsum, 16, 64);
    hsum += __shfl_xor(hsum, 32, 64);
    if (lane < 16) {  // one lane per expert per wave
        atomicAdd(&aS[e], ssum);
        atomicAdd(&aH[e], hsum);
    }
    __syncthreads();
    if (t < EE) {
        const float invB = 1.0f / (float)BB;
        atomicAdd(&avgs[t],      aS[t] * invB);
        atomicAdd(&avgs[EE + t], aH[t] * invB);
    }
}

// ---------------- K2: pure streaming combine y[b,d] = sum_e h[b,d,e]*sp[b,e] ----
__global__ __launch_bounds__(256) void combine_kernel(
    const float* __restrict__ h,      // [B, D, E]
    const float* __restrict__ sp_ws,  // [B, E]
    float* __restrict__ y)            // [B, D]
{
    const int t = threadIdx.x;
    const int b = blockIdx.x;
    const int q = t & 3;  // which float4-quad of the 16 experts this lane owns

    // each lane loads its 16B slice of the sp row (L1 broadcast within block)
    const float4 s4 = ((const float4*)(sp_ws + (size_t)b * EE))[q];

    const float4* h4 = (const float4*)(h + (size_t)b * DD * EE);
    float* yb = y + (size_t)b * DD;

    // 3072 float4-units per row; fully coalesced: lane t reads unit it*256+t
    #pragma unroll
    for (int it = 0; it < 12; ++it) {
        const int u = it * 256 + t;           // unit index; d = u>>2, quad = u&3
        float4 a = h4[u];
        float p = a.x * s4.x + a.y * s4.y + a.z * s4.z + a.w * s4.w;
        p += __shfl_xor(p, 1, 64);
        p += __shfl_xor(p, 2, 64);
        if (q == 0) yb[u >> 2] = p;
    }
}

extern "C" void kernel_launch(void* const* d_in, const int* in_sizes, int n_in,
                              void* d_out, int out_size, void* d_ws, size_t ws_size,
                              hipStream_t stream) {
    const float* h    = (const float*)d_in[0];   // [8192, 768, 16]
    const float* x    = (const float*)d_in[1];   // [8192, 768]
    const float* W    = (const float*)d_in[2];   // [16, 768]
    const float* bias = (const float*)d_in[3];   // [16]
    const float* Pw   = (const float*)d_in[4];   // [4, 16, 16]

    float* y    = (float*)d_out;                 // [8192, 768]
    float* avgs = y + (size_t)BB * DD;           // soft[16] ++ hard[16]
    float* sp_ws = (float*)d_ws;                 // [8192, 16] = 512 KB

    // zero the accumulator tail (atomics add into it every call)
    hipMemsetAsync(avgs, 0, 2 * EE * sizeof(float), stream);

    gating_kernel<<<BB / ROWS_PER_BLK, 256, 0, stream>>>(x, W, bias, Pw, sp_ws, avgs);
    combine_kernel<<<BB, 256, 0, stream>>>(h, sp_ws, y);
}

// Round 3
// 146.988 us; speedup vs baseline: 1.0326x; 1.0326x over previous
//
#include <hip/hip_runtime.h>
#include <math.h>

#define BB 8192
#define DD 768
#define EE 16
#define PP 4
#define RPB 4   // rows per block; grid = 8192/4 = 2048 blocks (guide G11 sweet spot)

__global__ __launch_bounds__(256, 4) void moe_fused(
    const float* __restrict__ h,      // [B, D, E]
    const float* __restrict__ x,      // [B, D]
    const float* __restrict__ W,      // [E, D]
    const float* __restrict__ bias,   // [E]
    const float* __restrict__ Pw,     // [P, E, E]
    float* __restrict__ y,            // [B, D]
    float* __restrict__ avgs)         // [32]: soft[16] ++ hard[16]
{
    __shared__ float Pm[EE * EE];
    __shared__ float sp_lds[RPB][EE];
    __shared__ float aS[EE], aH[EE];

    const int t    = threadIdx.x;
    const int w    = t >> 6;        // wave id == row within block
    const int lane = t & 63;
    const int e    = lane & 15;     // expert
    const int seg  = lane >> 4;     // k-segment 0..3
    const int row  = blockIdx.x * RPB + w;

    // ---- P_mean -> LDS (one entry per thread) ----
    {
        float s = 0.f;
        #pragma unroll
        for (int p = 0; p < PP; ++p) s += Pw[p * EE * EE + t];
        Pm[t] = s * 0.25f;
    }
    if (t < EE) { aS[t] = 0.f; aH[t] = 0.f; }
    __syncthreads();

    // ---- Phase A: router logit for (row, e); each lane dots 192 elems ----
    const float4* x4 = (const float4*)(x + (size_t)row * DD);
    const float4* w4 = (const float4*)(W + (size_t)e * DD);
    float4 acc = {0.f, 0.f, 0.f, 0.f};
    #pragma unroll 6
    for (int i = 0; i < 48; ++i) {
        const int k4 = seg + 4 * i;
        float4 a = x4[k4], b = w4[k4];
        acc.x = fmaf(a.x, b.x, acc.x);
        acc.y = fmaf(a.y, b.y, acc.y);
        acc.z = fmaf(a.z, b.z, acc.z);
        acc.w = fmaf(a.w, b.w, acc.w);
    }
    float part = (acc.x + acc.y) + (acc.z + acc.w);
    part += __shfl_xor(part, 16, 64);   // combine 4 k-segments
    part += __shfl_xor(part, 32, 64);
    const float logit = part + bias[e];

    // top-1 across the 16 experts (every lane ends with the winner)
    float v0 = logit; int i0 = e;
    #pragma unroll
    for (int m = 1; m < 16; m <<= 1) {
        float ov = __shfl_xor(v0, m, 16);
        int   oi = __shfl_xor(i0, m, 16);
        if (ov > v0 || (ov == v0 && oi < i0)) { v0 = ov; i0 = oi; }
    }
    // top-2: mask the winner, reduce again
    float v1 = (e == i0) ? -INFINITY : logit; int i1 = e;
    #pragma unroll
    for (int m = 1; m < 16; m <<= 1) {
        float ov = __shfl_xor(v1, m, 16);
        int   oi = __shfl_xor(i1, m, 16);
        if (ov > v1 || (ov == v1 && oi < i1)) { v1 = ov; i1 = oi; }
    }

    // reference quirk: scattered==0.0 -> -inf before softmax
    const float z0 = (v0 == 0.f) ? -INFINITY : v0;
    const float z1 = (v1 == 0.f) ? -INFINITY : v1;
    const float mx = fmaxf(z0, z1);
    const float e0 = expf(z0 - mx), e1 = expf(z1 - mx);
    const float inv = 1.f / (e0 + e1);
    const float sm0 = e0 * inv, sm1 = e1 * inv;

    // s_perm[row, e] = sm0*Pm[i0,e] + sm1*Pm[i1,e]
    const float s = sm0 * Pm[i0 * EE + e] + sm1 * Pm[i1 * EE + e];
    if (seg == 0) {
        sp_lds[w][e] = s;
        atomicAdd(&aS[e], s);
        atomicAdd(&aH[e], (s >= 1e-5f) ? 1.f : 0.f);
    }
    __syncthreads();

    // block-level averages -> 32 global atomics per block (2048 blocks)
    if (t < EE) {
        const float invB = 1.0f / (float)BB;
        atomicAdd(&avgs[t],      aS[t] * invB);
        atomicAdd(&avgs[EE + t], aH[t] * invB);
    }

    // ---- Phase B: stream h, fully coalesced; y[r,d] = sum_e h[r,d,e]*sp[r,e] ----
    const int q = t & 3;   // which expert-quad this lane owns
    for (int r = 0; r < RPB; ++r) {
        const float4 s4 = ((const float4*)&sp_lds[r][0])[q];
        const size_t rw = (size_t)(blockIdx.x * RPB + r);
        const float4* h4 = (const float4*)(h + rw * DD * EE);
        float* yr = y + rw * DD;
        #pragma unroll
        for (int it = 0; it < 12; ++it) {
            const int u = it * 256 + t;       // wave reads 1KB contiguous/instr
            float4 a = h4[u];
            float p = a.x * s4.x + a.y * s4.y + a.z * s4.z + a.w * s4.w;
            p += __shfl_xor(p, 1, 64);        // quad reduce (DPP, VALU-cheap)
            p += __shfl_xor(p, 2, 64);
            if (q == 0) yr[u >> 2] = p;
        }
    }
}

extern "C" void kernel_launch(void* const* d_in, const int* in_sizes, int n_in,
                              void* d_out, int out_size, void* d_ws, size_t ws_size,
                              hipStream_t stream) {
    const float* h    = (const float*)d_in[0];   // [8192, 768, 16]
    const float* x    = (const float*)d_in[1];   // [8192, 768]
    const float* W    = (const float*)d_in[2];   // [16, 768]
    const float* bias = (const float*)d_in[3];   // [16]
    const float* Pw   = (const float*)d_in[4];   // [4, 16, 16]

    float* y    = (float*)d_out;                 // [8192, 768]
    float* avgs = y + (size_t)BB * DD;           // soft[16] ++ hard[16]

    // zero the accumulator tail (atomics add into it every call)
    hipMemsetAsync(avgs, 0, 2 * EE * sizeof(float), stream);

    moe_fused<<<BB / RPB, 256, 0, stream>>>(h, x, W, bias, Pw, y, avgs);
}